// Round 4
// baseline (280.144 us; speedup 1.0000x reference)
//
#include <hip/hip_runtime.h>

// Problem constants (fixed by the reference)
#define BB 4
#define T 128           // T1 == T2
#define D 300
#define D4 75           // D/4 float4 chunks
#define NROW 512        // BB*T

// Session findings:
// - (prev session) hL/hR stream plateaus at ~2.4 TB/s regardless of
//   occupancy/async/LDS/L3-residency.
// - (R2) XCD swizzle: FETCH -6.6%, time FLAT -> HBM *bytes* not the limit.
// - (R1,R3) BOTH intra-kernel cross-workgroup dataflow attempts failed
//   correctness (cooperative launch; scratch+ticket across XCD L2s).
//   RULE: cross-block dataflow only at dispatch boundaries.
// - (R4, this) the one unmeasured variable: request payload. All prior
//   probes consumed hL/hR in 1200-B granules (1024B+176B per pair, 58%
//   avg payload); D2D copy at 6.3 TB/s uses full 1024-B requests. This
//   kernel makes every hL/hR/k access a contiguous >=4800-B run (89-100%
//   payload) via (b, 4i) blocks looping over 8j tiles, hR transposed
//   through LDS, everything block-local (no tickets).

// ---------------- Kernel A: projections q = x@WQ.T+bQ, k/v = x@WK.T+bK ----
__global__ __launch_bounds__(320) void proj_kernel(
    const float* __restrict__ query, const float* __restrict__ key,
    const float* __restrict__ value,
    const float* __restrict__ WQ, const float* __restrict__ bQ,
    const float* __restrict__ WK, const float* __restrict__ bK,
    float* __restrict__ qkv /* [3][512][300] */)
{
    const int src  = blockIdx.x >> 6;    // 0=q,1=k,2=v
    const int rblk = blockIdx.x & 63;
    const int r0   = rblk * 8;
    const float* in   = (src == 0) ? query : (src == 1 ? key : value);
    const float* W    = (src == 0) ? WQ : WK;
    const float* bias = (src == 0) ? bQ : bK;
    float* out = qkv + src * (NROW * D);

    __shared__ __align__(16) float lds_in[8 * D];   // 9.6 KB
    for (int idx = threadIdx.x; idx < 8 * D; idx += 320)
        lds_in[idx] = in[r0 * D + idx];
    __syncthreads();

    const int t = threadIdx.x;
    if (t < D) {
        float acc[8];
        const float bv = bias[t];
        #pragma unroll
        for (int r = 0; r < 8; ++r) acc[r] = bv;
        const float4* W4 = (const float4*)(W + t * D);
        for (int e4 = 0; e4 < D4; ++e4) {
            const float4 w = W4[e4];
            #pragma unroll
            for (int r = 0; r < 8; ++r) {
                const float4 x = *(const float4*)(&lds_in[r * D + e4 * 4]);
                acc[r] += w.x * x.x + w.y * x.y + w.z * x.z + w.w * x.w;
            }
        }
        #pragma unroll
        for (int r = 0; r < 8; ++r)
            out[(r0 + r) * D + t] = acc[r];
    }
}

// ------- Kernel B: block-local tiled scores + softmax + sparse output -----
// grid 128 = (b:4, it:32 of 4 rows), 512 threads (8 waves).
// Per jt-iter (16 iters of 8 j): stage hR[b,j0:j0+8,i0:i0+4,:] (8x4800B
// contiguous granules) + k[b,j0:j0+8,:] (9.6KB flat) to LDS; wave (iw,jh)
// reads hL[b,i,j0+4jh:+4,:] as a flat 4800B run and accumulates 4 scores.
__global__ __launch_bounds__(512) void attn3_kernel(
    const float* __restrict__ hL, const float* __restrict__ hR,
    const float* __restrict__ qkv, float* __restrict__ outp)
{
    // XCD-contiguous swizzle (128 = 8*16): 16 consecutive (b,it) per XCD.
    const int swz = (blockIdx.x & 7) * 16 + (blockIdx.x >> 3);
    const int b  = swz >> 5;          // 0..3
    const int it = swz & 31;          // 0..31
    const int i0 = it * 4;

    __shared__ __align__(16) float4 hR_l[2400];   // [8j][4i][75] 38.4 KB
    __shared__ __align__(16) float4 k_l[600];     // [8j][75]      9.6 KB
    __shared__ __align__(16) float4 q_l[300];     // [4i][75]      4.8 KB
    __shared__ float sc[4][T];                    //               2   KB

    const float4* hR4  = (const float4*)hR;
    const float4* hL4  = (const float4*)hL;
    const float4* qkv4 = (const float4*)qkv;

    // q tile once (300 contiguous float4)
    for (int idx = threadIdx.x; idx < 300; idx += 512)
        q_l[idx] = qkv4[(size_t)(b * T + i0) * D4 + idx];

    const int w    = threadIdx.x >> 6;   // 0..7
    const int lane = threadIdx.x & 63;
    const int iw   = w & 3;              // i-row within tile
    const int jh   = w >> 2;             // j-half (0,1)
    const int i    = i0 + iw;

    for (int jt = 0; jt < 16; ++jt) {
        const int j0 = jt * 8;
        // ---- stage hR tile: 8 granules of 300 f4 (4800B, contiguous) ----
        for (int idx = threadIdx.x; idx < 2400; idx += 512) {
            const int g = idx / 300, off = idx - g * 300;   // [i][d4] flat
            hR_l[idx] = hR4[((size_t)(b * T + j0 + g) * T + i0) * D4 + off];
        }
        // ---- stage k tile: 600 contiguous f4 ----
        for (int idx = threadIdx.x; idx < 600; idx += 512)
            k_l[idx] = qkv4[(size_t)NROW * D4 + (size_t)(b * T + j0) * D4 + idx];
        __syncthreads();

        // ---- scores: wave (iw,jh) covers hL[b,i,j0+4jh : +4, :] flat ----
        const float4* hLw = hL4 + ((size_t)(b * T + i) * T + j0 + jh * 4) * D4;
        float a0 = 0.f, a1 = 0.f, a2 = 0.f, a3 = 0.f;
        #pragma unroll
        for (int itr = 0; itr < 5; ++itr) {
            const int c = itr * 64 + lane;
            if (c < 4 * D4) {
                const int jl = c / D4, d4 = c - jl * D4;
                const int jg = jh * 4 + jl;             // 0..7 within tile
                const float4 hl = hLw[c];
                const float4 qq = q_l[iw * D4 + d4];
                const float4 kk = k_l[jg * D4 + d4];
                const float4 rr = hR_l[(jg * 4 + iw) * D4 + d4];
                const float s = (qq.x + hl.x) * (kk.x + rr.x)
                              + (qq.y + hl.y) * (kk.y + rr.y)
                              + (qq.z + hl.z) * (kk.z + rr.z)
                              + (qq.w + hl.w) * (kk.w + rr.w);
                a0 += (jl == 0) ? s : 0.f;
                a1 += (jl == 1) ? s : 0.f;
                a2 += (jl == 2) ? s : 0.f;
                a3 += (jl == 3) ? s : 0.f;
            }
        }
        #pragma unroll
        for (int off = 32; off > 0; off >>= 1) a0 += __shfl_xor(a0, off, 64);
        #pragma unroll
        for (int off = 32; off > 0; off >>= 1) a1 += __shfl_xor(a1, off, 64);
        #pragma unroll
        for (int off = 32; off > 0; off >>= 1) a2 += __shfl_xor(a2, off, 64);
        #pragma unroll
        for (int off = 32; off > 0; off >>= 1) a3 += __shfl_xor(a3, off, 64);
        if (lane == 0)
            *(float4*)(&sc[iw][j0 + jh * 4]) = make_float4(a0, a1, a2, a3);
        __syncthreads();   // protect LDS tiles before next stage
    }

    // ---- softmax + sharpening: wave r (r<4) owns row i0+r ----
    if (w < 4) {
        float s0 = sc[w][lane], s1 = sc[w][lane + 64];
        float m = fmaxf(s0, s1);
        #pragma unroll
        for (int off = 32; off > 0; off >>= 1) m = fmaxf(m, __shfl_xor(m, off, 64));
        float e0 = __expf(s0 - m), e1 = __expf(s1 - m);
        float sum = e0 + e1;
        #pragma unroll
        for (int off = 32; off > 0; off >>= 1) sum += __shfl_xor(sum, off, 64);
        const float inv = 1.0f / sum;
        float t0 = 1000.0f * (e0 * inv), t1 = 1000.0f * (e1 * inv);
        float m2 = fmaxf(t0, t1);
        #pragma unroll
        for (int off = 32; off > 0; off >>= 1) m2 = fmaxf(m2, __shfl_xor(m2, off, 64));
        float f0 = __expf(t0 - m2), f1 = __expf(t1 - m2);
        float sum2 = f0 + f1;
        #pragma unroll
        for (int off = 32; off > 0; off >>= 1) sum2 += __shfl_xor(sum2, off, 64);
        const float inv2 = 1.0f / sum2;
        sc[w][lane]      = fminf(fmaxf(f0 * inv2, 0.f), 1.f);
        sc[w][lane + 64] = fminf(fmaxf(f1 * inv2, 0.f), 1.f);
    }
    __syncthreads();

    // ---- pass 2: out[i0+row, d] = sum_j att_j * (v[j,d] + hR[j,i,d]) ----
    // Sharpened attn ~one-hot: skip avoids nearly all loads (survivors are
    // L2/L3-hot — this block streamed those hR granules already).
    const int row = threadIdx.x >> 7;       // 0..3
    const int r   = threadIdx.x & 127;
    if (r < D4) {
        const int d4 = r;
        const int ir = i0 + row;
        const float4* v4b = qkv4 + 2 * NROW * D4 + (size_t)(b * T) * D4;
        float4 acc = {0.f, 0.f, 0.f, 0.f};
        for (int j = 0; j < T; ++j) {
            const float aj = sc[row][j];
            if (aj >= 1e-12f) {   // skip error bound < 1e-9 << 0.104 threshold
                const float4 vv = v4b[j * D4 + d4];
                const float4 rr = hR4[((size_t)(b * T + j) * T + ir) * D4 + d4];
                acc.x += aj * (vv.x + rr.x);
                acc.y += aj * (vv.y + rr.y);
                acc.z += aj * (vv.z + rr.z);
                acc.w += aj * (vv.w + rr.w);
            }
        }
        ((float4*)outp)[(size_t)(b * T + ir) * D4 + d4] = acc;
    }
}

extern "C" void kernel_launch(void* const* d_in, const int* in_sizes, int n_in,
                              void* d_out, int out_size, void* d_ws, size_t ws_size,
                              hipStream_t stream) {
    const float* query = (const float*)d_in[0];
    const float* key   = (const float*)d_in[1];
    const float* value = (const float*)d_in[2];
    const float* hL    = (const float*)d_in[3];
    const float* hR    = (const float*)d_in[4];
    const float* WQ    = (const float*)d_in[5];
    const float* bQ    = (const float*)d_in[6];
    const float* WK    = (const float*)d_in[7];
    const float* bK    = (const float*)d_in[8];
    float* out = (float*)d_out;
    float* qkv = (float*)d_ws;   // 3*512*300*4 = 1.84 MB

    proj_kernel<<<dim3(192), dim3(320), 0, stream>>>(query, key, value, WQ, bQ, WK, bK, qkv);
    attn3_kernel<<<dim3(128), dim3(512), 0, stream>>>(hL, hR, qkv, out);
}

// Round 5
// 237.700 us; speedup vs baseline: 1.1786x; 1.1786x over previous
//
#include <hip/hip_runtime.h>

// Problem constants (fixed by the reference)
#define BB 4
#define T 128           // T1 == T2
#define D 300
#define D4 75           // D/4 float4 chunks
#define NROW 512        // BB*T

// Session findings:
// - (prev session) hL/hR stream plateaus at ~2.4 TB/s regardless of
//   occupancy(26-75%)/async-depth/LDS/L3-residency.
// - (R2) XCD swizzle: FETCH -6.6%, time FLAT -> bytes/lines not the limit.
// - (R1,R3) intra-kernel cross-workgroup dataflow fails correctness on this
//   part. RULE: cross-block dataflow only at dispatch boundaries.
// - (R4) full-payload probe CONFOUNDED: 128 blocks -> 11% occupancy, 117us.
//   Tiling math verified correct (absmax 0.0039).
// - (R5, this) full-payload at R2 parallelism: 512 score-blocks x 1024 thr
//   (2/CU), hR 94% payload, hL 78%, k staged; scores->scratch; separate
//   finish dispatch (softmax+sharpen+sparse pass2). 3 dispatches total.

// ---------------- Kernel A: projections q = x@WQ.T+bQ, k/v = x@WK.T+bK ----
__global__ __launch_bounds__(320) void proj_kernel(
    const float* __restrict__ query, const float* __restrict__ key,
    const float* __restrict__ value,
    const float* __restrict__ WQ, const float* __restrict__ bQ,
    const float* __restrict__ WK, const float* __restrict__ bK,
    float* __restrict__ qkv /* [3][512][300] */)
{
    const int src  = blockIdx.x >> 6;    // 0=q,1=k,2=v
    const int rblk = blockIdx.x & 63;
    const int r0   = rblk * 8;
    const float* in   = (src == 0) ? query : (src == 1 ? key : value);
    const float* W    = (src == 0) ? WQ : WK;
    const float* bias = (src == 0) ? bQ : bK;
    float* out = qkv + src * (NROW * D);

    __shared__ __align__(16) float lds_in[8 * D];   // 9.6 KB
    for (int idx = threadIdx.x; idx < 8 * D; idx += 320)
        lds_in[idx] = in[r0 * D + idx];
    __syncthreads();

    const int t = threadIdx.x;
    if (t < D) {
        float acc[8];
        const float bv = bias[t];
        #pragma unroll
        for (int r = 0; r < 8; ++r) acc[r] = bv;
        const float4* W4 = (const float4*)(W + t * D);
        for (int e4 = 0; e4 < D4; ++e4) {
            const float4 w = W4[e4];
            #pragma unroll
            for (int r = 0; r < 8; ++r) {
                const float4 x = *(const float4*)(&lds_in[r * D + e4 * 4]);
                acc[r] += w.x * x.x + w.y * x.y + w.z * x.z + w.w * x.w;
            }
        }
        #pragma unroll
        for (int r = 0; r < 8; ++r)
            out[(r0 + r) * D + t] = acc[r];
    }
}

// -------- Kernel B: full-payload tiled scores -> scB scratch --------------
// grid 512 = (b:4, it:32 [4 i-rows], jt:4 [32 j]) after XCD swizzle;
// 1024 threads (16 waves), 2 blocks/CU. Per sub-tile (8 j): stage
// hR[b,j00:j00+8, i0:i0+4, :] as 8x 4800B contiguous granules + k flat;
// wave (iw, jh) reads hL[b,i, j00+2jh : +2, :] as a flat 2400B run.
__global__ __launch_bounds__(1024) void score_kernel(
    const float* __restrict__ hL, const float* __restrict__ hR,
    const float* __restrict__ qkv, float* __restrict__ scB)
{
    // XCD-contiguous swizzle (512 = 8*64)
    const int swz = (blockIdx.x & 7) * 64 + (blockIdx.x >> 3);
    const int b  = swz >> 7;          // 0..3
    const int it = (swz >> 2) & 31;   // 0..31
    const int jt = swz & 3;           // 0..3
    const int i0 = it * 4, j0 = jt * 32;

    __shared__ __align__(16) float4 hR_l[2400];   // [8j][4i][75] 38.4 KB
    __shared__ __align__(16) float4 k_l[600];     // [8j][75]      9.6 KB
    __shared__ __align__(16) float4 q_l[300];     // [4i][75]      4.8 KB

    const float4* hR4  = (const float4*)hR;
    const float4* hL4  = (const float4*)hL;
    const float4* qkv4 = (const float4*)qkv;

    // q tile once (300 contiguous float4)
    for (int idx = threadIdx.x; idx < 300; idx += 1024)
        q_l[idx] = qkv4[(size_t)(b * T + i0) * D4 + idx];

    const int w    = threadIdx.x >> 6;   // 0..15
    const int lane = threadIdx.x & 63;
    const int iw   = w & 3;              // i-row within tile
    const int jh   = w >> 2;             // j-pair index (0..3)
    const int i    = i0 + iw;

    for (int js = 0; js < 4; ++js) {
        const int j00 = j0 + js * 8;
        // ---- stage hR: 8 granules of 300 f4 (4800B contiguous each) ----
        for (int idx = threadIdx.x; idx < 2400; idx += 1024) {
            const int g = idx / 300, off = idx - g * 300;   // [i][d4] flat
            hR_l[idx] = hR4[((size_t)(b * T + j00 + g) * T + i0) * D4 + off];
        }
        // ---- stage k: 600 contiguous f4 ----
        for (int idx = threadIdx.x; idx < 600; idx += 1024)
            k_l[idx] = qkv4[(size_t)NROW * D4 + (size_t)(b * T + j00) * D4 + idx];
        __syncthreads();

        // ---- wave (iw,jh): hL[b,i, j00+2jh : +2, :] flat (150 f4) ----
        const float4* hLw = hL4 + ((size_t)(b * T + i) * T + j00 + jh * 2) * D4;
        float a0 = 0.f, a1 = 0.f;
        #pragma unroll
        for (int itr = 0; itr < 3; ++itr) {
            const int c = itr * 64 + lane;
            if (c < 2 * D4) {
                const int jl = c / D4, d4 = c - jl * D4;
                const int jg = jh * 2 + jl;             // 0..7 within sub-tile
                const float4 hl = hLw[c];
                const float4 qq = q_l[iw * D4 + d4];
                const float4 kk = k_l[jg * D4 + d4];
                const float4 rr = hR_l[(jg * 4 + iw) * D4 + d4];
                const float s = (qq.x + hl.x) * (kk.x + rr.x)
                              + (qq.y + hl.y) * (kk.y + rr.y)
                              + (qq.z + hl.z) * (kk.z + rr.z)
                              + (qq.w + hl.w) * (kk.w + rr.w);
                a0 += (jl == 0) ? s : 0.f;
                a1 += (jl == 1) ? s : 0.f;
            }
        }
        #pragma unroll
        for (int off = 32; off > 0; off >>= 1) a0 += __shfl_xor(a0, off, 64);
        #pragma unroll
        for (int off = 32; off > 0; off >>= 1) a1 += __shfl_xor(a1, off, 64);
        if (lane == 0)
            *(float2*)(&scB[((b * T + i) << 7) + j00 + jh * 2]) = make_float2(a0, a1);
        __syncthreads();   // protect LDS tiles before next stage
    }
}

// -------- Kernel C: softmax + sharpening + sparse pass 2 ------------------
// grid 512 (one per b,i), 128 threads (2 waves).
__global__ __launch_bounds__(128) void finish_kernel(
    const float* __restrict__ hR, const float* __restrict__ qkv,
    const float* __restrict__ scB, float* __restrict__ outp)
{
    const int b = blockIdx.x >> 7;
    const int i = blockIdx.x & 127;
    __shared__ float att[T];

    const int tid  = threadIdx.x;
    const int lane = tid & 63;
    if (tid < 64) {
        const int row = (b * T + i) << 7;
        float s0 = scB[row + lane], s1 = scB[row + 64 + lane];
        float m = fmaxf(s0, s1);
        #pragma unroll
        for (int off = 32; off > 0; off >>= 1) m = fmaxf(m, __shfl_xor(m, off, 64));
        float e0 = __expf(s0 - m), e1 = __expf(s1 - m);
        float sum = e0 + e1;
        #pragma unroll
        for (int off = 32; off > 0; off >>= 1) sum += __shfl_xor(sum, off, 64);
        const float inv = 1.0f / sum;
        float t0 = 1000.0f * (e0 * inv), t1 = 1000.0f * (e1 * inv);
        float m2 = fmaxf(t0, t1);
        #pragma unroll
        for (int off = 32; off > 0; off >>= 1) m2 = fmaxf(m2, __shfl_xor(m2, off, 64));
        float f0 = __expf(t0 - m2), f1 = __expf(t1 - m2);
        float sum2 = f0 + f1;
        #pragma unroll
        for (int off = 32; off > 0; off >>= 1) sum2 += __shfl_xor(sum2, off, 64);
        const float inv2 = 1.0f / sum2;
        att[lane]      = fminf(fmaxf(f0 * inv2, 0.f), 1.f);
        att[lane + 64] = fminf(fmaxf(f1 * inv2, 0.f), 1.f);
    }
    __syncthreads();

    // pass 2: sharpened attn ~one-hot; skip avoids nearly all loads.
    if (tid < D4) {
        const float4* qkv4 = (const float4*)qkv;
        const float4* hR4  = (const float4*)hR;
        const float4* v4b  = qkv4 + 2 * NROW * D4 + (size_t)(b * T) * D4;
        float4 acc = {0.f, 0.f, 0.f, 0.f};
        for (int j = 0; j < T; ++j) {
            const float aj = att[j];
            if (aj >= 1e-12f) {   // skip error bound < 1e-9 << 0.104 threshold
                const float4 vv = v4b[j * D4 + tid];
                const float4 rr = hR4[((size_t)(b * T + j) * T + i) * D4 + tid];
                acc.x += aj * (vv.x + rr.x);
                acc.y += aj * (vv.y + rr.y);
                acc.z += aj * (vv.z + rr.z);
                acc.w += aj * (vv.w + rr.w);
            }
        }
        ((float4*)outp)[(size_t)(b * T + i) * D4 + tid] = acc;
    }
}

extern "C" void kernel_launch(void* const* d_in, const int* in_sizes, int n_in,
                              void* d_out, int out_size, void* d_ws, size_t ws_size,
                              hipStream_t stream) {
    const float* query = (const float*)d_in[0];
    const float* key   = (const float*)d_in[1];
    const float* value = (const float*)d_in[2];
    const float* hL    = (const float*)d_in[3];
    const float* hR    = (const float*)d_in[4];
    const float* WQ    = (const float*)d_in[5];
    const float* bQ    = (const float*)d_in[6];
    const float* WK    = (const float*)d_in[7];
    const float* bK    = (const float*)d_in[8];
    float* out = (float*)d_out;
    float* qkv = (float*)d_ws;                 // 3*512*300*4 = 1.843 MB
    float* scB = qkv + 3 * NROW * D;           // [4][128][128] = 256 KB

    proj_kernel<<<dim3(192), dim3(320), 0, stream>>>(query, key, value, WQ, bQ, WK, bK, qkv);
    score_kernel<<<dim3(512), dim3(1024), 0, stream>>>(hL, hR, qkv, scB);
    finish_kernel<<<dim3(512), dim3(128), 0, stream>>>(hR, qkv, scB, out);
}

// Round 6
// 215.289 us; speedup vs baseline: 1.3012x; 1.1041x over previous
//
#include <hip/hip_runtime.h>

// Problem constants (fixed by the reference)
#define BB 4
#define T 128           // T1 == T2
#define D 300
#define D4 75           // D/4 float4 chunks
#define NROW 512        // BB*T

// Session findings:
// - hL/hR stream plateaus at 2.42 TB/s = EXACTLY 1 x 128B line/cy/XCD.
//   Falsified: bytes (R2 dedup -6.6% flat), occupancy (11%->72% flat above
//   40%), async-depth/reg pipelines (prev), L3-residency (prev), request
//   payload/contiguity (R5: 94%-payload staging == scattered 1200B, both
//   65us). 3rd dispatch costs +10us e2e (R5) -> stay at 2 dispatches.
// - Remaining mechanism consistent with ALL data: per-XCD L2 line-fill/
//   allocation rate ~1 line/cycle. This round's probe: non-temporal loads
//   (nt bit) on the read-once hL/hR streams to bypass L2 allocation.
// - (R1,R3) intra-kernel cross-workgroup dataflow fails correctness here.
//   RULE: cross-block dataflow only at dispatch boundaries.

typedef float nf4 __attribute__((ext_vector_type(4)));
__device__ __forceinline__ float4 ntload4(const float4* p) {
    nf4 v = __builtin_nontemporal_load((const nf4*)p);
    union { nf4 a; float4 b; } u; u.a = v; return u.b;
}

// ---------------- Kernel A: projections q = x@WQ.T+bQ, k/v = x@WK.T+bK ----
__global__ __launch_bounds__(320) void proj_kernel(
    const float* __restrict__ query, const float* __restrict__ key,
    const float* __restrict__ value,
    const float* __restrict__ WQ, const float* __restrict__ bQ,
    const float* __restrict__ WK, const float* __restrict__ bK,
    float* __restrict__ qkv /* [3][512][300] */)
{
    const int src  = blockIdx.x >> 6;    // 0=q,1=k,2=v
    const int rblk = blockIdx.x & 63;
    const int r0   = rblk * 8;
    const float* in   = (src == 0) ? query : (src == 1 ? key : value);
    const float* W    = (src == 0) ? WQ : WK;
    const float* bias = (src == 0) ? bQ : bK;
    float* out = qkv + src * (NROW * D);

    __shared__ __align__(16) float lds_in[8 * D];   // 9.6 KB
    for (int idx = threadIdx.x; idx < 8 * D; idx += 320)
        lds_in[idx] = in[r0 * D + idx];
    __syncthreads();

    const int t = threadIdx.x;
    if (t < D) {
        float acc[8];
        const float bv = bias[t];
        #pragma unroll
        for (int r = 0; r < 8; ++r) acc[r] = bv;
        const float4* W4 = (const float4*)(W + t * D);
        for (int e4 = 0; e4 < D4; ++e4) {
            const float4 w = W4[e4];
            #pragma unroll
            for (int r = 0; r < 8; ++r) {
                const float4 x = *(const float4*)(&lds_in[r * D + e4 * 4]);
                acc[r] += w.x * x.x + w.y * x.y + w.z * x.z + w.w * x.w;
            }
        }
        #pragma unroll
        for (int r = 0; r < 8; ++r)
            out[(r0 + r) * D + t] = acc[r];
    }
}

// ---------------- Kernel B: fused scores -> double softmax -> output ------
// grid: 512 blocks (one per (b,i) after swizzle), 1024 threads (16 waves).
// R2 baseline + NT loads on the read-once hL/hR pass-1 streams.
__global__ __launch_bounds__(1024) void attn_kernel(
    const float* __restrict__ hL, const float* __restrict__ hR,
    const float* __restrict__ qkv, float* __restrict__ outp)
{
    // XCD-contiguous swizzle: (bid&7) is the XCD id; contiguous 64-runs.
    const int swz = (blockIdx.x & 7) * 64 + (blockIdx.x >> 3);
    const int b = swz >> 7;
    const int i = swz & 127;

    const float* qp    = qkv + (b * T + i) * D;
    const float* kbase = qkv + NROW * D + b * T * D;
    const float* vbase = qkv + 2 * NROW * D + b * T * D;

    __shared__ __align__(16) float q_lds[D];
    __shared__ float sc[T];
    __shared__ __align__(16) float red[12][D];   // 14.4 KB

    for (int idx = threadIdx.x; idx < D; idx += 1024) q_lds[idx] = qp[idx];
    __syncthreads();

    const int wave = threadIdx.x >> 6;   // 0..15
    const int lane = threadIdx.x & 63;

    // ---- pass 1: scores[j] = sum_d (q_d + hL[i,j,d]) * (k_jd + hR[j,i,d]) ----
    const float4* hL4 = (const float4*)(hL + (size_t)(b * T + i) * T * D);
    for (int j = wave; j < T; j += 16) {       // 8 iterations per wave
        const float4* hRrow = (const float4*)(hR + ((size_t)(b * T + j) * T + i) * D);
        const float4* krow  = (const float4*)(kbase + j * D);
        float4 a = {0.f, 0.f, 0.f, 0.f};
        #pragma unroll
        for (int it = 0; it < 2; ++it) {
            const int d4 = lane + it * 64;
            if (d4 < D4) {
                const float4 l  = ntload4(&hL4[j * D4 + d4]);   // NT: read-once
                const float4 r  = ntload4(&hRrow[d4]);          // NT: read-once
                const float4 kk = krow[d4];
                const float4 qq = *(const float4*)(&q_lds[d4 * 4]);
                a.x += (qq.x + l.x) * (kk.x + r.x);
                a.y += (qq.y + l.y) * (kk.y + r.y);
                a.z += (qq.z + l.z) * (kk.z + r.z);
                a.w += (qq.w + l.w) * (kk.w + r.w);
            }
        }
        float s = a.x + a.y + a.z + a.w;
        #pragma unroll
        for (int off = 32; off > 0; off >>= 1)
            s += __shfl_down(s, off, 64);
        if (lane == 0) sc[j] = s;
    }
    __syncthreads();

    // ---- softmax + sharpening (wave 0 only; 2 scores per lane) ----
    if (wave == 0) {
        float s0 = sc[lane], s1 = sc[lane + 64];
        float m = fmaxf(s0, s1);
        #pragma unroll
        for (int off = 32; off > 0; off >>= 1) m = fmaxf(m, __shfl_xor(m, off, 64));
        float e0 = __expf(s0 - m), e1 = __expf(s1 - m);
        float sum = e0 + e1;
        #pragma unroll
        for (int off = 32; off > 0; off >>= 1) sum += __shfl_xor(sum, off, 64);
        const float inv = 1.0f / sum;
        // sharpen: softmax(1000 * p), clamp to [0,1]
        float t0 = 1000.0f * (e0 * inv), t1 = 1000.0f * (e1 * inv);
        float m2 = fmaxf(t0, t1);
        #pragma unroll
        for (int off = 32; off > 0; off >>= 1) m2 = fmaxf(m2, __shfl_xor(m2, off, 64));
        float f0 = __expf(t0 - m2), f1 = __expf(t1 - m2);
        float sum2 = f0 + f1;
        #pragma unroll
        for (int off = 32; off > 0; off >>= 1) sum2 += __shfl_xor(sum2, off, 64);
        const float inv2 = 1.0f / sum2;
        sc[lane]      = fminf(fmaxf(f0 * inv2, 0.f), 1.f);
        sc[lane + 64] = fminf(fmaxf(f1 * inv2, 0.f), 1.f);
    }
    __syncthreads();

    // ---- pass 2: out[d] = sum_j attn_j * (v[j,d] + hR[j,i,d]) ----
    // Sharpened attn is ~one-hot: the 1e-12 skip avoids nearly all loads.
    // Pass-2 loads stay CACHED (survivors may re-hit L3; they are few).
    const int tid = threadIdx.x;
    if (tid < 12 * D4) {
        const int grp = tid / D4;    // 0..11: j-split
        const int d4  = tid % D4;
        float4 acc = {0.f, 0.f, 0.f, 0.f};
        for (int j = grp; j < T; j += 12) {
            const float aj = sc[j];
            if (aj >= 1e-12f) {      // skip error bound < 1e-9 << 0.104 threshold
                const float4 v4 = *(const float4*)(vbase + j * D + d4 * 4);
                const float4 r4 = *(const float4*)(hR + ((size_t)(b * T + j) * T + i) * D + d4 * 4);
                acc.x += aj * (v4.x + r4.x);
                acc.y += aj * (v4.y + r4.y);
                acc.z += aj * (v4.z + r4.z);
                acc.w += aj * (v4.w + r4.w);
            }
        }
        *(float4*)(&red[grp][d4 * 4]) = acc;
    }
    __syncthreads();
    if (tid < D4) {
        float4 o = {0.f, 0.f, 0.f, 0.f};
        #pragma unroll
        for (int g = 0; g < 12; ++g) {
            const float4 p = *(const float4*)(&red[g][tid * 4]);
            o.x += p.x; o.y += p.y; o.z += p.z; o.w += p.w;
        }
        *(float4*)(outp + (size_t)(b * T + i) * D + tid * 4) = o;
    }
}

extern "C" void kernel_launch(void* const* d_in, const int* in_sizes, int n_in,
                              void* d_out, int out_size, void* d_ws, size_t ws_size,
                              hipStream_t stream) {
    const float* query = (const float*)d_in[0];
    const float* key   = (const float*)d_in[1];
    const float* value = (const float*)d_in[2];
    const float* hL    = (const float*)d_in[3];
    const float* hR    = (const float*)d_in[4];
    const float* WQ    = (const float*)d_in[5];
    const float* bQ    = (const float*)d_in[6];
    const float* WK    = (const float*)d_in[7];
    const float* bK    = (const float*)d_in[8];
    float* out = (float*)d_out;
    float* qkv = (float*)d_ws;   // 3*512*300*4 = 1.84 MB

    proj_kernel<<<dim3(192), dim3(320), 0, stream>>>(query, key, value, WQ, bQ, WK, bK, qkv);
    attn_kernel<<<dim3(512), dim3(1024), 0, stream>>>(hL, hR, qkv, out);
}